// Round 8
// baseline (50.934 us; speedup 1.0000x reference)
//
#include <hip/hip_runtime.h>

namespace {
constexpr int N_ELEMS  = 262144;
constexpr int N_NODES  = 263169;
constexpr int NTHREADS = N_ELEMS * 2;     // thread t -> element t/2, ip pair (t&1, (t&1)+2)
constexpr int BLK      = 256;
constexpr int NBLOCKS  = NTHREADS / BLK;  // 2048 partial-sum slots

// folded material constants (fp32, match reference math)
constexpr float GC_2L0  = 0.09f;                 // G_C / (2*L_0)
constexpr float L0SQ    = 0.015f * 0.015f;
constexpr float MU_     = 80.76923076923077f;    // E/(2(1+nu))
constexpr float K_MOD   = 175.0f;                // lam + 2mu/3 (exact)
constexpr float PENALTY = 1799.82f;              // G_C/L_0*(1/PF_TOL^2-1)
}

typedef float vfloat4 __attribute__((ext_vector_type(4)));
typedef int   vint4   __attribute__((ext_vector_type(4)));

__device__ __forceinline__ float waveReduce(float x) {
#pragma unroll
    for (int off = 32; off; off >>= 1) x += __shfl_down(x, off, 64);
    return x;
}

// __launch_bounds__(256, 4): 4 blocks/CU -> 16 waves/CU cap, VGPR budget 128.
// Latency-bound kernel: we trade nominal occupancy headroom for enough VGPRs
// to keep all ~26 loads per thread in flight (one waitcnt drain, not 3-4).
__global__ __launch_bounds__(256, 4) void fused_energy(
    const float* __restrict__ u, const float* __restrict__ v,
    const float* __restrict__ c, const float* __restrict__ prev_c,
    const int* __restrict__ conn,
    const float* __restrict__ Nf, const float* __restrict__ dNdx,
    const float* __restrict__ B, const float* __restrict__ vol,
    float* __restrict__ partials)
{
    const int t = blockIdx.x * blockDim.x + threadIdx.x;   // 0..NTHREADS-1
    const int e    = t >> 1;
    const int iplo = t & 1;            // this thread: ip = iplo and iplo+2
    const bool ev  = (iplo == 0);      // lane parity == t parity (BLK % 64 == 0)

    // ---- dense loads (all independent, issued up front) ------------------
    const vint4 cn = *reinterpret_cast<const vint4*>(conn + 4ll * e);

    const vfloat4 NrA = *reinterpret_cast<const vfloat4*>(Nf + 16ll * e + 4 * iplo);
    const vfloat4 NrB = *reinterpret_cast<const vfloat4*>(Nf + 16ll * e + 4 * iplo + 8);

    const float* Dp = dNdx + 32ll * e + 8 * iplo;
    const vfloat4 dxA = *reinterpret_cast<const vfloat4*>(Dp);
    const vfloat4 dyA = *reinterpret_cast<const vfloat4*>(Dp + 4);
    const vfloat4 dxB = *reinterpret_cast<const vfloat4*>(Dp + 16);
    const vfloat4 dyB = *reinterpret_cast<const vfloat4*>(Dp + 20);

    const float* Bp = B + 96ll * e + 24 * iplo;
    const vfloat4 a0 = *reinterpret_cast<const vfloat4*>(Bp +  0);
    const vfloat4 a1 = *reinterpret_cast<const vfloat4*>(Bp +  4);
    const vfloat4 a2 = *reinterpret_cast<const vfloat4*>(Bp +  8);
    const vfloat4 a3 = *reinterpret_cast<const vfloat4*>(Bp + 12);
    const vfloat4 a4 = *reinterpret_cast<const vfloat4*>(Bp + 16);
    const vfloat4 a5 = *reinterpret_cast<const vfloat4*>(Bp + 20);
    const vfloat4 q0 = *reinterpret_cast<const vfloat4*>(Bp + 48);
    const vfloat4 q1 = *reinterpret_cast<const vfloat4*>(Bp + 52);
    const vfloat4 q2 = *reinterpret_cast<const vfloat4*>(Bp + 56);
    const vfloat4 q3 = *reinterpret_cast<const vfloat4*>(Bp + 60);
    const vfloat4 q4 = *reinterpret_cast<const vfloat4*>(Bp + 64);
    const vfloat4 q5 = *reinterpret_cast<const vfloat4*>(Bp + 68);

    const float vipA = vol[4ll * e + iplo];
    const float vipB = vol[4ll * e + iplo + 2];

    float Eirr = 0.f;
    if (t < N_NODES) {
        float d = fmaxf(prev_c[t] - c[t], 0.f);
        Eirr = 0.5f * PENALTY * d * d;
    }

    // ---- split gathers: even lane takes {c0..c3,u0,u1}, odd {v0..v3,u2,u3}
    const float* A  = ev ? c : v;
    const int  idx4 = ev ? cn.x : cn.z;
    const int  idx5 = ev ? cn.y : cn.w;
    const float g0 = A[cn.x], g1 = A[cn.y], g2 = A[cn.z], g3 = A[cn.w];
    const float g4 = u[idx4], g5 = u[idx5];

    const float p0 = __shfl_xor(g0, 1);
    const float p1 = __shfl_xor(g1, 1);
    const float p2 = __shfl_xor(g2, 1);
    const float p3 = __shfl_xor(g3, 1);
    const float p4 = __shfl_xor(g4, 1);
    const float p5 = __shfl_xor(g5, 1);

    const float c0 = ev ? g0 : p0, c1 = ev ? g1 : p1;
    const float c2 = ev ? g2 : p2, c3 = ev ? g3 : p3;
    const float v0 = ev ? p0 : g0, v1 = ev ? p1 : g1;
    const float v2 = ev ? p2 : g2, v3 = ev ? p3 : g3;
    const float u0 = ev ? g4 : p4, u1 = ev ? g5 : p5;
    const float u2 = ev ? p4 : g4, u3 = ev ? p5 : g5;

    // ---- compute ---------------------------------------------------------
    const float o0 = 1.f - c0, o1 = 1.f - c1, o2 = 1.f - c2, o3 = 1.f - c3;

    float Eel = 0.f, Efr = 0.f;
    {   // unit A: ip = iplo
        const float omc = NrA.x * o0 + NrA.y * o1 + NrA.z * o2 + NrA.w * o3;
        const float g = omc * omc, cip = 1.f - omc;
        const float gx = dxA.x * c0 + dxA.y * c1 + dxA.z * c2 + dxA.w * c3;
        const float gy = dyA.x * c0 + dyA.y * c1 + dyA.z * c2 + dyA.w * c3;
        Efr += GC_2L0 * (cip * cip + L0SQ * (gx * gx + gy * gy)) * vipA;

        const float exx = a0.x * u0 + a0.y * v0 + a0.z * u1 + a0.w * v1
                        + a1.x * u2 + a1.y * v2 + a1.z * u3 + a1.w * v3;
        const float eyy = a2.x * u0 + a2.y * v0 + a2.z * u1 + a2.w * v1
                        + a3.x * u2 + a3.y * v2 + a3.z * u3 + a3.w * v3;
        const float gxy = a4.x * u0 + a4.y * v0 + a4.z * u1 + a4.w * v1
                        + a5.x * u2 + a5.y * v2 + a5.z * u3 + a5.w * v3;
        const float exy = 0.5f * gxy;
        const float tr = exx + eyy, tr3 = tr * (1.f / 3.f);
        const float dxx = exx - tr3, dyy = eyy - tr3, dzz = -tr3;
        const float dev2 = dxx * dxx + dyy * dyy + dzz * dzz + 2.f * exy * exy;
        const float trp = fmaxf(tr, 0.f), trn = fminf(tr, 0.f);
        Eel += ((0.5f * K_MOD * trp * trp + MU_ * dev2) * g
                + 0.5f * K_MOD * trn * trn) * vipA;
    }
    {   // unit B: ip = iplo + 2
        const float omc = NrB.x * o0 + NrB.y * o1 + NrB.z * o2 + NrB.w * o3;
        const float g = omc * omc, cip = 1.f - omc;
        const float gx = dxB.x * c0 + dxB.y * c1 + dxB.z * c2 + dxB.w * c3;
        const float gy = dyB.x * c0 + dyB.y * c1 + dyB.z * c2 + dyB.w * c3;
        Efr += GC_2L0 * (cip * cip + L0SQ * (gx * gx + gy * gy)) * vipB;

        const float exx = q0.x * u0 + q0.y * v0 + q0.z * u1 + q0.w * v1
                        + q1.x * u2 + q1.y * v2 + q1.z * u3 + q1.w * v3;
        const float eyy = q2.x * u0 + q2.y * v0 + q2.z * u1 + q2.w * v1
                        + q3.x * u2 + q3.y * v2 + q3.z * u3 + q3.w * v3;
        const float gxy = q4.x * u0 + q4.y * v0 + q4.z * u1 + q4.w * v1
                        + q5.x * u2 + q5.y * v2 + q5.z * u3 + q5.w * v3;
        const float exy = 0.5f * gxy;
        const float tr = exx + eyy, tr3 = tr * (1.f / 3.f);
        const float dxx = exx - tr3, dyy = eyy - tr3, dzz = -tr3;
        const float dev2 = dxx * dxx + dyy * dyy + dzz * dzz + 2.f * exy * exy;
        const float trp = fmaxf(tr, 0.f), trn = fminf(tr, 0.f);
        Eel += ((0.5f * K_MOD * trp * trp + MU_ * dev2) * g
                + 0.5f * K_MOD * trn * trn) * vipB;
    }

    // ---- block reduction → contention-free partial store -----------------
    Eel  = waveReduce(Eel);
    Efr  = waveReduce(Efr);
    Eirr = waveReduce(Eirr);
    __shared__ float sE[4], sF[4], sI[4];
    const int lane = threadIdx.x & 63, wid = threadIdx.x >> 6;
    if (lane == 0) { sE[wid] = Eel; sF[wid] = Efr; sI[wid] = Eirr; }
    __syncthreads();
    if (threadIdx.x == 0) {
        float* p = partials + 3ll * blockIdx.x;
        p[0] = sE[0] + sE[1] + sE[2] + sE[3];
        p[1] = sF[0] + sF[1] + sF[2] + sF[3];
        p[2] = sI[0] + sI[1] + sI[2] + sI[3];
    }
}

__global__ __launch_bounds__(256) void final_reduce(
    const float* __restrict__ partials, float* __restrict__ out)
{
    float s0 = 0.f, s1 = 0.f, s2 = 0.f;
    for (int i = threadIdx.x; i < NBLOCKS; i += 256) {
        const float* p = partials + 3ll * i;
        s0 += p[0]; s1 += p[1]; s2 += p[2];
    }
    s0 = waveReduce(s0);
    s1 = waveReduce(s1);
    s2 = waveReduce(s2);
    __shared__ float sA[4], sB[4], sC[4];
    const int lane = threadIdx.x & 63, wid = threadIdx.x >> 6;
    if (lane == 0) { sA[wid] = s0; sB[wid] = s1; sC[wid] = s2; }
    __syncthreads();
    if (threadIdx.x == 0) {
        out[0] = sA[0] + sA[1] + sA[2] + sA[3];
        out[1] = sB[0] + sB[1] + sB[2] + sB[3];
        out[2] = sC[0] + sC[1] + sC[2] + sC[3];
    }
}

extern "C" void kernel_launch(void* const* d_in, const int* in_sizes, int n_in,
                              void* d_out, int out_size, void* d_ws, size_t ws_size,
                              hipStream_t stream) {
    const float* u      = (const float*)d_in[0];
    const float* v      = (const float*)d_in[1];
    const float* c      = (const float*)d_in[2];
    const float* prev_c = (const float*)d_in[3];
    const int*   conn   = (const int*)d_in[4];
    const float* Nf     = (const float*)d_in[5];
    const float* dNdx   = (const float*)d_in[6];
    const float* B      = (const float*)d_in[7];
    const float* vol    = (const float*)d_in[8];
    float* out      = (float*)d_out;
    float* partials = (float*)d_ws;   // 2048 * 3 floats = 24 KB

    fused_energy<<<NBLOCKS, BLK, 0, stream>>>(
        u, v, c, prev_c, conn, Nf, dNdx, B, vol, partials);
    final_reduce<<<1, BLK, 0, stream>>>(partials, out);
}

// Round 9
// 46.885 us; speedup vs baseline: 1.0864x; 1.0864x over previous
//
#include <hip/hip_runtime.h>

namespace {
constexpr int N_ELEMS   = 262144;
constexpr int N_NODES   = 263169;
constexpr int BLK       = 256;
constexpr int EPB       = 128;               // elements per block (2 lanes/elem)
constexpr int NBLOCKS   = N_ELEMS / EPB;     // 2048
constexpr int ROWS      = 24;                // f4-index within element
constexpr int ROWSTRIDE = EPB + 1;           // 129 f4s per row (pad breaks conflicts)

// folded material constants (fp32, match reference math)
constexpr float GC_2L0  = 0.09f;                 // G_C / (2*L_0)
constexpr float L0SQ    = 0.015f * 0.015f;
constexpr float MU_     = 80.76923076923077f;    // E/(2(1+nu))
constexpr float K_MOD   = 175.0f;                // lam + 2mu/3 (exact)
constexpr float PENALTY = 1799.82f;              // G_C/L_0*(1/PF_TOL^2-1)
}

typedef float vfloat4 __attribute__((ext_vector_type(4)));
typedef int   vint4   __attribute__((ext_vector_type(4)));

__device__ __forceinline__ float waveReduce(float x) {
#pragma unroll
    for (int off = 32; off; off >>= 1) x += __shfl_down(x, off, 64);
    return x;
}

__global__ __launch_bounds__(256) void fused_energy(
    const float* __restrict__ u, const float* __restrict__ v,
    const float* __restrict__ c, const float* __restrict__ prev_c,
    const int* __restrict__ conn,
    const float* __restrict__ Nf, const float* __restrict__ dNdx,
    const float* __restrict__ B, const float* __restrict__ vol,
    float* __restrict__ partials)
{
    // f4-major B tile: row = f4-index (0..23), col = element-in-tile (0..127).
    // Reads: lanes of a wave hit CONSECUTIVE cols -> lane-contiguous LDS reads.
    __shared__ vfloat4 ldsB[ROWS * ROWSTRIDE];   // 24*129*16 = 49,536 B

    const int k     = threadIdx.x;
    const int ebase = blockIdx.x * EPB;
    const int t     = blockIdx.x * BLK + k;      // for the nodal term

    // ---- stage B tile: 3072 f4s as a pure unit-stride stream -------------
    const vfloat4* Bg = reinterpret_cast<const vfloat4*>(B) + (long long)ebase * 24;
#pragma unroll
    for (int r = 0; r < 12; ++r) {
        const int j = k + BLK * r;               // tile-linear f4 index
        const vfloat4 val = Bg[j];               // lane-contiguous global load
        ldsB[(j % 24) * ROWSTRIDE + (j / 24)] = val;
    }

    // ---- other per-element loads (as R7) ---------------------------------
    const int e    = ebase + (k >> 1);
    const int iplo = k & 1;
    const bool ev  = (iplo == 0);

    const vint4 cn = *reinterpret_cast<const vint4*>(conn + 4ll * e);

    const vfloat4 NrA = *reinterpret_cast<const vfloat4*>(Nf + 16ll * e + 4 * iplo);
    const vfloat4 NrB = *reinterpret_cast<const vfloat4*>(Nf + 16ll * e + 4 * iplo + 8);

    const float* Dp = dNdx + 32ll * e + 8 * iplo;
    const vfloat4 dxA = *reinterpret_cast<const vfloat4*>(Dp);
    const vfloat4 dyA = *reinterpret_cast<const vfloat4*>(Dp + 4);
    const vfloat4 dxB = *reinterpret_cast<const vfloat4*>(Dp + 16);
    const vfloat4 dyB = *reinterpret_cast<const vfloat4*>(Dp + 20);

    const float vipA = vol[4ll * e + iplo];
    const float vipB = vol[4ll * e + iplo + 2];

    float Eirr = 0.f;
    if (t < N_NODES) {
        float d = fmaxf(prev_c[t] - c[t], 0.f);
        Eirr = 0.5f * PENALTY * d * d;
    }

    // ---- split gathers + shuffle exchange (as R7) ------------------------
    const float* A  = ev ? c : v;
    const int  idx4 = ev ? cn.x : cn.z;
    const int  idx5 = ev ? cn.y : cn.w;
    const float g0 = A[cn.x], g1 = A[cn.y], g2 = A[cn.z], g3 = A[cn.w];
    const float g4 = u[idx4], g5 = u[idx5];

    const float p0 = __shfl_xor(g0, 1);
    const float p1 = __shfl_xor(g1, 1);
    const float p2 = __shfl_xor(g2, 1);
    const float p3 = __shfl_xor(g3, 1);
    const float p4 = __shfl_xor(g4, 1);
    const float p5 = __shfl_xor(g5, 1);

    const float c0 = ev ? g0 : p0, c1 = ev ? g1 : p1;
    const float c2 = ev ? g2 : p2, c3 = ev ? g3 : p3;
    const float v0 = ev ? p0 : g0, v1 = ev ? p1 : g1;
    const float v2 = ev ? p2 : g2, v3 = ev ? p3 : g3;
    const float u0 = ev ? g4 : p4, u1 = ev ? g5 : p5;
    const float u2 = ev ? p4 : g4, u3 = ev ? p5 : g5;

    __syncthreads();

    // ---- read this thread's B fragments from LDS (lane-contiguous) -------
    const int m = k >> 1;                        // element within tile
    const int rbase = 6 * iplo;
    const vfloat4 a0 = ldsB[(rbase + 0) * ROWSTRIDE + m];
    const vfloat4 a1 = ldsB[(rbase + 1) * ROWSTRIDE + m];
    const vfloat4 a2 = ldsB[(rbase + 2) * ROWSTRIDE + m];
    const vfloat4 a3 = ldsB[(rbase + 3) * ROWSTRIDE + m];
    const vfloat4 a4 = ldsB[(rbase + 4) * ROWSTRIDE + m];
    const vfloat4 a5 = ldsB[(rbase + 5) * ROWSTRIDE + m];
    const vfloat4 q0 = ldsB[(12 + rbase + 0) * ROWSTRIDE + m];
    const vfloat4 q1 = ldsB[(12 + rbase + 1) * ROWSTRIDE + m];
    const vfloat4 q2 = ldsB[(12 + rbase + 2) * ROWSTRIDE + m];
    const vfloat4 q3 = ldsB[(12 + rbase + 3) * ROWSTRIDE + m];
    const vfloat4 q4 = ldsB[(12 + rbase + 4) * ROWSTRIDE + m];
    const vfloat4 q5 = ldsB[(12 + rbase + 5) * ROWSTRIDE + m];

    // ---- compute ---------------------------------------------------------
    const float o0 = 1.f - c0, o1 = 1.f - c1, o2 = 1.f - c2, o3 = 1.f - c3;

    float Eel = 0.f, Efr = 0.f;
    {   // unit A: ip = iplo
        const float omc = NrA.x * o0 + NrA.y * o1 + NrA.z * o2 + NrA.w * o3;
        const float g = omc * omc, cip = 1.f - omc;
        const float gx = dxA.x * c0 + dxA.y * c1 + dxA.z * c2 + dxA.w * c3;
        const float gy = dyA.x * c0 + dyA.y * c1 + dyA.z * c2 + dyA.w * c3;
        Efr += GC_2L0 * (cip * cip + L0SQ * (gx * gx + gy * gy)) * vipA;

        const float exx = a0.x * u0 + a0.y * v0 + a0.z * u1 + a0.w * v1
                        + a1.x * u2 + a1.y * v2 + a1.z * u3 + a1.w * v3;
        const float eyy = a2.x * u0 + a2.y * v0 + a2.z * u1 + a2.w * v1
                        + a3.x * u2 + a3.y * v2 + a3.z * u3 + a3.w * v3;
        const float gxy = a4.x * u0 + a4.y * v0 + a4.z * u1 + a4.w * v1
                        + a5.x * u2 + a5.y * v2 + a5.z * u3 + a5.w * v3;
        const float exy = 0.5f * gxy;
        const float tr = exx + eyy, tr3 = tr * (1.f / 3.f);
        const float dxx = exx - tr3, dyy = eyy - tr3, dzz = -tr3;
        const float dev2 = dxx * dxx + dyy * dyy + dzz * dzz + 2.f * exy * exy;
        const float trp = fmaxf(tr, 0.f), trn = fminf(tr, 0.f);
        Eel += ((0.5f * K_MOD * trp * trp + MU_ * dev2) * g
                + 0.5f * K_MOD * trn * trn) * vipA;
    }
    {   // unit B: ip = iplo + 2
        const float omc = NrB.x * o0 + NrB.y * o1 + NrB.z * o2 + NrB.w * o3;
        const float g = omc * omc, cip = 1.f - omc;
        const float gx = dxB.x * c0 + dxB.y * c1 + dxB.z * c2 + dxB.w * c3;
        const float gy = dyB.x * c0 + dyB.y * c1 + dyB.z * c2 + dyB.w * c3;
        Efr += GC_2L0 * (cip * cip + L0SQ * (gx * gx + gy * gy)) * vipB;

        const float exx = q0.x * u0 + q0.y * v0 + q0.z * u1 + q0.w * v1
                        + q1.x * u2 + q1.y * v2 + q1.z * u3 + q1.w * v3;
        const float eyy = q2.x * u0 + q2.y * v0 + q2.z * u1 + q2.w * v1
                        + q3.x * u2 + q3.y * v2 + q3.z * u3 + q3.w * v3;
        const float gxy = q4.x * u0 + q4.y * v0 + q4.z * u1 + q4.w * v1
                        + q5.x * u2 + q5.y * v2 + q5.z * u3 + q5.w * v3;
        const float exy = 0.5f * gxy;
        const float tr = exx + eyy, tr3 = tr * (1.f / 3.f);
        const float dxx = exx - tr3, dyy = eyy - tr3, dzz = -tr3;
        const float dev2 = dxx * dxx + dyy * dyy + dzz * dzz + 2.f * exy * exy;
        const float trp = fmaxf(tr, 0.f), trn = fminf(tr, 0.f);
        Eel += ((0.5f * K_MOD * trp * trp + MU_ * dev2) * g
                + 0.5f * K_MOD * trn * trn) * vipB;
    }

    // ---- block reduction -> contention-free partial store ----------------
    Eel  = waveReduce(Eel);
    Efr  = waveReduce(Efr);
    Eirr = waveReduce(Eirr);
    __shared__ float sE[4], sF[4], sI[4];
    const int lane = k & 63, wid = k >> 6;
    if (lane == 0) { sE[wid] = Eel; sF[wid] = Efr; sI[wid] = Eirr; }
    __syncthreads();
    if (k == 0) {
        float* p = partials + 3ll * blockIdx.x;
        p[0] = sE[0] + sE[1] + sE[2] + sE[3];
        p[1] = sF[0] + sF[1] + sF[2] + sF[3];
        p[2] = sI[0] + sI[1] + sI[2] + sI[3];
    }
}

__global__ __launch_bounds__(256) void final_reduce(
    const float* __restrict__ partials, float* __restrict__ out)
{
    float s0 = 0.f, s1 = 0.f, s2 = 0.f;
    for (int i = threadIdx.x; i < NBLOCKS; i += 256) {
        const float* p = partials + 3ll * i;
        s0 += p[0]; s1 += p[1]; s2 += p[2];
    }
    s0 = waveReduce(s0);
    s1 = waveReduce(s1);
    s2 = waveReduce(s2);
    __shared__ float sA[4], sB[4], sC[4];
    const int lane = threadIdx.x & 63, wid = threadIdx.x >> 6;
    if (lane == 0) { sA[wid] = s0; sB[wid] = s1; sC[wid] = s2; }
    __syncthreads();
    if (threadIdx.x == 0) {
        out[0] = sA[0] + sA[1] + sA[2] + sA[3];
        out[1] = sB[0] + sB[1] + sB[2] + sB[3];
        out[2] = sC[0] + sC[1] + sC[2] + sC[3];
    }
}

extern "C" void kernel_launch(void* const* d_in, const int* in_sizes, int n_in,
                              void* d_out, int out_size, void* d_ws, size_t ws_size,
                              hipStream_t stream) {
    const float* u      = (const float*)d_in[0];
    const float* v      = (const float*)d_in[1];
    const float* c      = (const float*)d_in[2];
    const float* prev_c = (const float*)d_in[3];
    const int*   conn   = (const int*)d_in[4];
    const float* Nf     = (const float*)d_in[5];
    const float* dNdx   = (const float*)d_in[6];
    const float* B      = (const float*)d_in[7];
    const float* vol    = (const float*)d_in[8];
    float* out      = (float*)d_out;
    float* partials = (float*)d_ws;   // 2048 * 3 floats = 24 KB

    fused_energy<<<NBLOCKS, BLK, 0, stream>>>(
        u, v, c, prev_c, conn, Nf, dNdx, B, vol, partials);
    final_reduce<<<1, BLK, 0, stream>>>(partials, out);
}